// Round 7
// baseline (211.926 us; speedup 1.0000x reference)
//
#include <hip/hip_runtime.h>
#include <cstdint>
#include <cstddef>

typedef unsigned short u16;
typedef unsigned int   u32;
using short8 = __attribute__((ext_vector_type(8))) short;
using f32x4  = __attribute__((ext_vector_type(4))) float;

// B=8, N=8192, H=256, A=64 (F=320), S=32
#define NB    8
#define NN    8192
#define HH    256
#define FF    320
#define SS    32
#define NROWS 65536
#define NCH   32            // pooling K-split chunks (256 n each)

__device__ __forceinline__ u16 f2bf(float f) {
    union { float f; u32 u; } v; v.f = f;
    u32 r = v.u + 0x7fffu + ((v.u >> 16) & 1u);   // RNE
    return (u16)(r >> 16);
}
// HW packed f32->bf16 (RNE). No builtin on gfx950 -> inline asm (T12 recipe).
__device__ __forceinline__ u32 pk2(float lo, float hi) {
    u32 r;
    asm("v_cvt_pk_bf16_f32 %0, %1, %2" : "=v"(r) : "v"(lo), "v"(hi));
    return r;
}

// ---------------- prep: cast x -> bf16 (A operand), Wi|Wj -> bf16, zero normsq ----
__global__ __launch_bounds__(256) void prep_all(
    const float* __restrict__ x, const float* __restrict__ Wi,
    const float* __restrict__ Wj,
    u16* __restrict__ xb16, u16* __restrict__ Wb, float* __restrict__ normsq)
{
    int gid = blockIdx.x * 256 + threadIdx.x;      // 0..524287
    #pragma unroll
    for (int i = 0; i < 5; ++i) {
        size_t o = (size_t)gid + (size_t)i * 524288;   // octet index
        const float4* s = reinterpret_cast<const float4*>(x + o * 8);
        float4 a = s[0], b = s[1];
        union { u32 u[4]; uint4 v; } r;
        r.u[0] = pk2(a.x, a.y); r.u[1] = pk2(a.z, a.w);
        r.u[2] = pk2(b.x, b.y); r.u[3] = pk2(b.z, b.w);
        *reinterpret_cast<uint4*>(xb16 + o * 8) = r.v;
    }
    if (gid < 163840) {
        float v = (gid < 81920) ? Wi[gid] : Wj[gid - 81920];
        Wb[gid] = f2bf(v);
    }
    if (gid < NROWS) normsq[gid] = 0.f;
}

// ---------------- kernel 1: gated features + norm^2 ----------------
// v7: TLP restructure. R3-R6 invariant: every 2-waves-per-SIMD config lands at 48-50 us
// regardless of mt/pinning -> per-wave serial chain (vmcnt->lgkm->MFMA) is exposed and
// 2 waves can't interleave it. Gate pairs (i,j) at same h, so min col-tile = 64
// (32 h x 2 mats): resident B drops to 40 KB, regs to ~100 (acc 32 + ring 32 + addr)
// -> 4 waves/SIMD, 2 blocks/CU, 32 waves/CU (2x TLP), co-resident blocks staggered.
// Block: 512 thr / 8 waves, 256 rows x 64 cols, wave owns 32 rows (mt=2).
// Grid 2048: xcd = bx&7, ht = (bx>>3)&7 -> 8 h-tiles of one m-tile share an XCD.
__global__ __launch_bounds__(512, 4) void gemm_gate(
    const u16* __restrict__ xb16, const u16* __restrict__ Wb,
    const float* __restrict__ bi, const float* __restrict__ bj,
    u16* __restrict__ xa, float* __restrict__ normsq)
{
    __shared__ u16 lB[5 * 4096];      // [kt][row 0..63][swizzled k-slot*8], 40960 B

    const int bx   = blockIdx.x;      // 0..2047
    const int xcd  = bx & 7;
    const int ht   = (bx >> 3) & 7;   // 0..7 (32 h each)
    const int slot = bx >> 6;         // 0..31
    const int mb   = xcd + slot * 8;  // 0..255
    const int m0   = mb * 256;
    const int h0   = ht * 32;
    const int b_idx = m0 >> 13;
    const int n0    = m0 & 8191;

    const int tid  = threadIdx.x;
    const int w    = tid >> 6;        // 0..7
    const int lane = tid & 63;
    const int quad = lane >> 4;
    const int l15  = lane & 15;

    // ---- one-time B load: 5 kt x 1 issue per wave (8 issues of 1 KB per kt) ----
    {
        const int rsub = lane >> 3;                 // 0..7
        const int kg   = (lane & 7) ^ rsub;         // XOR swizzle
        const int row  = w * 8 + rsub;              // 0..63
        const int mat  = row >> 5, hl = row & 31;
        #pragma unroll
        for (int kt = 0; kt < 5; ++kt) {
            const u16* gsrc = Wb + mat * 81920 + (size_t)(h0 + hl) * FF + kt * 64 + kg * 8;
            u16* ldst = &lB[kt * 4096 + w * 512];
            __builtin_amdgcn_global_load_lds(
                (const __attribute__((address_space(1))) void*)gsrc,
                (__attribute__((address_space(3))) void*)ldst, 16, 0, 0);
        }
    }

    // ---- A fragment addressing: row = m0 + w*32 + mt*16 + l15, k = ks*32 + quad*8 ----
    const u16* xb = xb16 + (size_t)(m0 + w * 32 + l15) * FF + quad * 8;

    f32x4 acc[4][2];                  // [mn (col/16)][mt]; mn 0-1 = mat i, 2-3 = mat j
    #pragma unroll
    for (int a = 0; a < 4; ++a)
        #pragma unroll
        for (int m = 0; m < 2; ++m) acc[a][m] = (f32x4){0.f, 0.f, 0.f, 0.f};

    short8 pre[4][2];                 // ring of 4 slots: prefetch distance 3
    #pragma unroll
    for (int p = 0; p < 3; ++p)
        #pragma unroll
        for (int mt = 0; mt < 2; ++mt)
            pre[p][mt] = *reinterpret_cast<const short8*>(xb + mt * 16 * FF + p * 32);

    __syncthreads();                  // B resident

    #pragma unroll
    for (int ks = 0; ks < 10; ++ks) {
        const int cur = ks & 3;
        if (ks < 7) {
            const int nxt = (ks + 3) & 3;
            const int f   = (ks + 3) * 32;
            #pragma unroll
            for (int mt = 0; mt < 2; ++mt)
                pre[nxt][mt] = *reinterpret_cast<const short8*>(xb + mt * 16 * FF + f);
        }
        // pin prefetch issue before this ks's compute group
        __builtin_amdgcn_sched_barrier(0);
        const int kt = ks >> 1, kk = ks & 1;
        #pragma unroll
        for (int mn = 0; mn < 4; ++mn) {
            int c = mn * 16 + l15;
            short8 bv = *reinterpret_cast<const short8*>(
                &lB[kt * 4096 + c * 64 + (((kk * 4 + quad) ^ (c & 7)) << 3)]);
            acc[mn][0] = __builtin_amdgcn_mfma_f32_16x16x32_bf16(pre[cur][0], bv, acc[mn][0], 0, 0, 0);
            acc[mn][1] = __builtin_amdgcn_mfma_f32_16x16x32_bf16(pre[cur][1], bv, acc[mn][1], 0, 0, 0);
        }
    }

    // ---- epilogue: gate (yi = mn 0-1, yj = mn 2-3), store xa [b][h][n], norm^2 ----
    float s0[2][4];
    #pragma unroll
    for (int mt = 0; mt < 2; ++mt)
        #pragma unroll
        for (int r = 0; r < 4; ++r) s0[mt][r] = 0.f;

    #pragma unroll
    for (int hq = 0; hq < 2; ++hq) {
        int h = h0 + hq * 16 + l15;
        float bi_v = bi[h], bj_v = bj[h];
        #pragma unroll
        for (int mt = 0; mt < 2; ++mt) {
            float xall[4];
            #pragma unroll
            for (int r = 0; r < 4; ++r) {
                float yi = acc[hq][mt][r] + bi_v;
                float yj = acc[hq + 2][mt][r] + bj_v;
                float sg = 1.f / (1.f + __expf(-yi));
                float e2 = __expf(-2.f * yj);
                float th = (1.f - e2) / (1.f + e2);
                float xv = sg * th;
                xall[r] = xv;
                s0[mt][r] += xv * xv;
            }
            uint2 pk;
            pk.x = pk2(xall[0], xall[1]);
            pk.y = pk2(xall[2], xall[3]);
            size_t o = (size_t)b_idx * ((size_t)HH * NN) + (size_t)h * NN
                     + (size_t)(n0 + w * 32 + mt * 16 + quad * 4);
            *reinterpret_cast<uint2*>(&xa[o]) = pk;
        }
    }
    #pragma unroll
    for (int m = 1; m <= 8; m <<= 1) {
        #pragma unroll
        for (int mt = 0; mt < 2; ++mt)
            #pragma unroll
            for (int r = 0; r < 4; ++r)
                s0[mt][r] += __shfl_xor(s0[mt][r], m, 64);
    }
    if (l15 == 0) {
        #pragma unroll
        for (int mt = 0; mt < 2; ++mt)
            #pragma unroll
            for (int r = 0; r < 4; ++r)
                atomicAdd(&normsq[m0 + w * 32 + mt * 16 + quad * 4 + r], s0[mt][r]);
    }
}

// ---------------- kernel 2: masked softmax over N per (b,s) -> out1 fp32 ----------------
__global__ __launch_bounds__(1024) void softmax_k(
    const float* __restrict__ nm, const float* __restrict__ normsq,
    float* __restrict__ out1)
{
    __shared__ float red[16];
    int bs = blockIdx.x;                 // 0..255
    int b  = bs >> 5;
    const float* src = nm + (size_t)bs * NN;
    float* dst       = out1 + (size_t)bs * NN;
    const float* ns  = normsq + (size_t)b * NN;
    int tid = threadIdx.x;
    float e[8];
    float sum = 0.f;
    #pragma unroll
    for (int i = 0; i < 8; ++i) {
        int n = i * 1024 + tid;
        float logit = src[n] * sqrtf(ns[n]);
        float v = (logit > 0.f) ? __expf(logit) : 0.f;
        e[i] = v;
        sum += v;
    }
    #pragma unroll
    for (int m = 1; m <= 32; m <<= 1) sum += __shfl_xor(sum, m, 64);
    int w = tid >> 6, lane = tid & 63;
    if (lane == 0) red[w] = sum;
    __syncthreads();
    float part = 0.f;
    #pragma unroll
    for (int j = 0; j < 16; ++j) part += red[j];
    float inv = (part > 0.f) ? (1.f / part) : 0.f;
    #pragma unroll
    for (int i = 0; i < 8; ++i) dst[i * 1024 + tid] = e[i] * inv;
}

// ---------------- kernel 3: pooling GEMM partials over 256-n chunks ----------------
// h-split x4 -> grid 1024 (4 blocks/CU = 16 waves/CU); bx%8 invariant in ht -> 4
// ht-blocks of one (b,c) share an XCD -> shared wgt slice L2-local.
__global__ __launch_bounds__(256) void pooled_k(
    const u16* __restrict__ xa, const float* __restrict__ wgt,
    float* __restrict__ part)
{
    __shared__ u16 lw[32 * 264];         // [s][k] stride 264 shorts (528 B)
    int bx = blockIdx.x;                 // 0..1023
    int ht = bx >> 8;                    // 0..3
    int bc = bx & 255;
    int b  = bc >> 5, c = bc & 31;
    int n0 = c * 256;
    int tid = threadIdx.x, w = tid >> 6, lane = tid & 63, quad = lane >> 4, l15 = lane & 15;

    // stage weights fp32 -> bf16 (32 s x 256 n); thread: s = tid>>3, n-sub = (tid&7)*32
    {
        int s  = tid >> 3;
        int nb = (tid & 7) * 32;
        const float* src = wgt + (size_t)(b * SS + s) * NN + n0 + nb;
        #pragma unroll
        for (int q = 0; q < 8; ++q) {
            float4 v = *reinterpret_cast<const float4*>(src + q * 4);
            uint2 pk;
            pk.x = pk2(v.x, v.y);
            pk.y = pk2(v.z, v.w);
            *reinterpret_cast<uint2*>(&lw[s * 264 + nb + q * 4]) = pk;
        }
    }
    __syncthreads();

    f32x4 acc[2];                        // [st]
    acc[0] = (f32x4){0.f, 0.f, 0.f, 0.f};
    acc[1] = (f32x4){0.f, 0.f, 0.f, 0.f};

    // A rows = h (16 per wave), k = n
    const u16* ab = xa + (size_t)b * ((size_t)HH * NN)
                  + (size_t)(ht * 64 + w * 16 + l15) * NN + n0;
    #pragma unroll
    for (int ks = 0; ks < 8; ++ks) {
        short8 av = *reinterpret_cast<const short8*>(ab + ks * 32 + quad * 8);
        #pragma unroll
        for (int st = 0; st < 2; ++st) {
            int s = st * 16 + l15;
            short8 bv = *reinterpret_cast<const short8*>(&lw[s * 264 + ks * 32 + quad * 8]);
            acc[st] = __builtin_amdgcn_mfma_f32_16x16x32_bf16(av, bv, acc[st], 0, 0, 0);
        }
    }
    float* pb = part + (size_t)(b * NCH + c) * 8192;   // [s*256 + h]
    #pragma unroll
    for (int st = 0; st < 2; ++st) {
        int h = ht * 64 + w * 16 + quad * 4;
        int s = st * 16 + l15;
        *reinterpret_cast<f32x4*>(&pb[s * 256 + h]) = acc[st];
    }
}

// ---------------- kernel 4: reduce partials over 32 chunks + tanh -> out0 ----------------
__global__ __launch_bounds__(256) void reduce_tanh(const float* __restrict__ part,
                                                   float* __restrict__ out0)
{
    int gid = blockIdx.x * 256 + threadIdx.x;   // 0..65535 = b*8192 + s*256 + h
    int b = gid >> 13, r = gid & 8191;
    const float* p = part + (size_t)b * NCH * 8192 + r;
    float s = 0.f;
    #pragma unroll
    for (int c = 0; c < NCH; ++c) s += p[(size_t)c * 8192];
    out0[gid] = tanhf(s);
}

extern "C" void kernel_launch(void* const* d_in, const int* in_sizes, int n_in,
                              void* d_out, int out_size, void* d_ws, size_t ws_size,
                              hipStream_t stream) {
    const float* x  = (const float*)d_in[0];
    const float* nm = (const float*)d_in[1];
    const float* Wi = (const float*)d_in[2];
    const float* bi = (const float*)d_in[3];
    const float* Wj = (const float*)d_in[4];
    const float* bj = (const float*)d_in[5];
    float* out0 = (float*)d_out;
    float* out1 = out0 + NB * SS * HH;           // 65536

    char* ws = (char*)d_ws;
    u16*   Wb     = (u16*)ws;                                    //    327,680 B
    u16*   xb16   = (u16*)(ws + 327680);                         // 41,943,040 B
    u16*   xa     = (u16*)(ws + 327680 + 41943040);              // 33,554,432 B
    float* normsq = (float*)(ws + 327680 + 41943040 + 33554432); //    262,144 B
    float* part   = (float*)(ws + 327680 + 41943040 + 33554432 + 262144); // 8,388,608 B

    prep_all   <<<2048, 256, 0, stream>>>(x, Wi, Wj, xb16, Wb, normsq);
    gemm_gate  <<<2048, 512, 0, stream>>>(xb16, Wb, bi, bj, xa, normsq);
    softmax_k  <<<256, 1024, 0, stream>>>(nm, normsq, out1);
    pooled_k   <<<1024, 256, 0, stream>>>(xa, out1, part);
    reduce_tanh<<<256,  256, 0, stream>>>(part, out0);
}

// Round 8
// 198.455 us; speedup vs baseline: 1.0679x; 1.0679x over previous
//
#include <hip/hip_runtime.h>
#include <cstdint>
#include <cstddef>

typedef unsigned short u16;
typedef unsigned int   u32;
using short8 = __attribute__((ext_vector_type(8))) short;
using f32x4  = __attribute__((ext_vector_type(4))) float;

// B=8, N=8192, H=256, A=64 (F=320), S=32
#define NB    8
#define NN    8192
#define HH    256
#define FF    320
#define SS    32
#define NROWS 65536
#define NCH   32            // pooling K-split chunks (256 n each)

__device__ __forceinline__ u16 f2bf(float f) {
    union { float f; u32 u; } v; v.f = f;
    u32 r = v.u + 0x7fffu + ((v.u >> 16) & 1u);   // RNE
    return (u16)(r >> 16);
}
// HW packed f32->bf16 (RNE). No builtin on gfx950 -> inline asm (T12 recipe).
__device__ __forceinline__ u32 pk2(float lo, float hi) {
    u32 r;
    asm("v_cvt_pk_bf16_f32 %0, %1, %2" : "=v"(r) : "v"(lo), "v"(hi));
    return r;
}
__device__ __forceinline__ short8 pack8(float4 a, float4 b) {
    union { u32 u[4]; short8 s; } r;
    r.u[0] = pk2(a.x, a.y); r.u[1] = pk2(a.z, a.w);
    r.u[2] = pk2(b.x, b.y); r.u[3] = pk2(b.z, b.w);
    return r.s;
}

// ---------------- prep: cast Wi,Wj to bf16 (concat) + zero normsq ----------------
// x pre-cast ELIMINATED (R7 decision): gemm reads x fp32 directly, saving the 84 MB
// read + 42 MB write prep leg (~23 us) and 42 MB of xb16 re-read.
__global__ __launch_bounds__(256) void prep_w(const float* __restrict__ Wi,
                                              const float* __restrict__ Wj,
                                              u16* __restrict__ Wb,
                                              float* __restrict__ normsq) {
    int idx = blockIdx.x * 256 + threadIdx.x;       // 0..163839
    float v = (idx < 81920) ? Wi[idx] : Wj[idx - 81920];
    Wb[idx] = f2bf(v);
    if (idx < NROWS) normsq[idx] = 0.f;
}

// ---------------- kernel 1: gated features + norm^2 ----------------
// R2 topology (proven 49 us): 512 thr / 8 waves, 256 rows x 128 cols, wave owns 32 rows
// (mt=2), B full-K resident in LDS (80 KB, one barrier), grid 1024 XCD-swizzled.
// CHANGE (R8): A read as fp32 float4-pairs ring-prefetched 3 deep, converted to the bf16
// MFMA fragment at use via v_cvt_pk_bf16_f32 (4 instr/fragment). Tests dtype-vs-depth
// (R1 vs R2 never isolated it) while deleting the x-cast pipeline.
// Regs: acc 64 + fp32 ring 64 + addr -> ~170 unified; launch_bounds(512,3) (forcing 4
// would spill the ring). LDS caps at 2 blocks/CU regardless.
__global__ __launch_bounds__(512, 3) void gemm_gate(
    const float* __restrict__ x, const u16* __restrict__ Wb,
    const float* __restrict__ bi, const float* __restrict__ bj,
    u16* __restrict__ xa, float* __restrict__ normsq)
{
    __shared__ u16 lB[5 * 8192];      // [kt][row 0..127][swizzled k-slot*8], 81920 B

    const int bx   = blockIdx.x;
    const int xcd  = bx & 7;
    const int ht   = (bx >> 3) & 3;
    const int slot = bx >> 5;         // 0..31
    const int mb   = xcd + slot * 8;  // 0..255
    const int m0   = mb * 256;
    const int h0   = ht * 64;
    const int b_idx = m0 >> 13;
    const int n0    = m0 & 8191;

    const int tid  = threadIdx.x;
    const int w    = tid >> 6;        // 0..7
    const int lane = tid & 63;
    const int quad = lane >> 4;
    const int l15  = lane & 15;

    // ---- one-time B load: 5 kt x 2 issues per wave (16 issues of 1 KB per kt) ----
    {
        const int rsub = lane >> 3;                 // 0..7
        const int kg   = (lane & 7) ^ rsub;         // XOR swizzle
        #pragma unroll
        for (int kt = 0; kt < 5; ++kt) {
            #pragma unroll
            for (int j = 0; j < 2; ++j) {
                int sl  = w * 2 + j;                // 0..15
                int row = sl * 8 + rsub;            // 0..127
                int mat = row >> 6, hl = row & 63;
                const u16* gsrc = Wb + mat * 81920 + (size_t)(h0 + hl) * FF + kt * 64 + kg * 8;
                u16* ldst = &lB[kt * 8192 + sl * 512];
                __builtin_amdgcn_global_load_lds(
                    (const __attribute__((address_space(1))) void*)gsrc,
                    (__attribute__((address_space(3))) void*)ldst, 16, 0, 0);
            }
        }
    }

    // ---- A fragment addressing: row = m0 + w*32 + mt*16 + l15, k = ks*32 + quad*8 ----
    const float* xb = x + (size_t)(m0 + w * 32 + l15) * FF + quad * 8;

    f32x4 acc[8][2];                  // [mn(col/16)][mt]
    #pragma unroll
    for (int a = 0; a < 8; ++a)
        #pragma unroll
        for (int m = 0; m < 2; ++m) acc[a][m] = (f32x4){0.f, 0.f, 0.f, 0.f};

    float4 pre[4][2][2];              // ring of 4 slots x mt x (lo,hi): depth 3
    #pragma unroll
    for (int p = 0; p < 3; ++p)
        #pragma unroll
        for (int mt = 0; mt < 2; ++mt) {
            pre[p][mt][0] = *reinterpret_cast<const float4*>(xb + mt * 16 * FF + p * 32);
            pre[p][mt][1] = *reinterpret_cast<const float4*>(xb + mt * 16 * FF + p * 32 + 4);
        }

    __syncthreads();                  // B resident

    #pragma unroll
    for (int ks = 0; ks < 10; ++ks) {
        const int cur = ks & 3;
        if (ks < 7) {
            const int nxt = (ks + 3) & 3;
            const int f   = (ks + 3) * 32;
            #pragma unroll
            for (int mt = 0; mt < 2; ++mt) {
                pre[nxt][mt][0] = *reinterpret_cast<const float4*>(xb + mt * 16 * FF + f);
                pre[nxt][mt][1] = *reinterpret_cast<const float4*>(xb + mt * 16 * FF + f + 4);
            }
        }
        // pin prefetch issue before this ks's compute group (R6: neutral-to-positive)
        __builtin_amdgcn_sched_barrier(0);
        short8 af[2];
        #pragma unroll
        for (int mt = 0; mt < 2; ++mt)
            af[mt] = pack8(pre[cur][mt][0], pre[cur][mt][1]);
        const int kt = ks >> 1, kk = ks & 1;
        #pragma unroll
        for (int mn = 0; mn < 8; ++mn) {
            int c = mn * 16 + l15;
            short8 bv = *reinterpret_cast<const short8*>(
                &lB[kt * 8192 + c * 64 + (((kk * 4 + quad) ^ (c & 7)) << 3)]);
            acc[mn][0] = __builtin_amdgcn_mfma_f32_16x16x32_bf16(af[0], bv, acc[mn][0], 0, 0, 0);
            acc[mn][1] = __builtin_amdgcn_mfma_f32_16x16x32_bf16(af[1], bv, acc[mn][1], 0, 0, 0);
        }
    }

    // ---- epilogue: gate, store xa [b][h][n], norm^2 ----
    float s0[2][4];
    #pragma unroll
    for (int mt = 0; mt < 2; ++mt)
        #pragma unroll
        for (int r = 0; r < 4; ++r) s0[mt][r] = 0.f;

    #pragma unroll
    for (int hq = 0; hq < 4; ++hq) {
        int h = h0 + hq * 16 + l15;
        float bi_v = bi[h], bj_v = bj[h];
        #pragma unroll
        for (int mt = 0; mt < 2; ++mt) {
            float xall[4];
            #pragma unroll
            for (int r = 0; r < 4; ++r) {
                float yi = acc[hq][mt][r] + bi_v;
                float yj = acc[hq + 4][mt][r] + bj_v;
                float sg = 1.f / (1.f + __expf(-yi));
                float e2 = __expf(-2.f * yj);
                float th = (1.f - e2) / (1.f + e2);
                float xv = sg * th;
                xall[r] = xv;
                s0[mt][r] += xv * xv;
            }
            uint2 pk;
            pk.x = pk2(xall[0], xall[1]);
            pk.y = pk2(xall[2], xall[3]);
            size_t o = (size_t)b_idx * ((size_t)HH * NN) + (size_t)h * NN
                     + (size_t)(n0 + w * 32 + mt * 16 + quad * 4);
            *reinterpret_cast<uint2*>(&xa[o]) = pk;
        }
    }
    #pragma unroll
    for (int m = 1; m <= 8; m <<= 1) {
        #pragma unroll
        for (int mt = 0; mt < 2; ++mt)
            #pragma unroll
            for (int r = 0; r < 4; ++r)
                s0[mt][r] += __shfl_xor(s0[mt][r], m, 64);
    }
    if (l15 == 0) {
        #pragma unroll
        for (int mt = 0; mt < 2; ++mt)
            #pragma unroll
            for (int r = 0; r < 4; ++r)
                atomicAdd(&normsq[m0 + w * 32 + mt * 16 + quad * 4 + r], s0[mt][r]);
    }
}

// ---------------- kernel 2: masked softmax over N per (b,s) -> out1 fp32 ----------------
__global__ __launch_bounds__(1024) void softmax_k(
    const float* __restrict__ nm, const float* __restrict__ normsq,
    float* __restrict__ out1)
{
    __shared__ float red[16];
    int bs = blockIdx.x;                 // 0..255
    int b  = bs >> 5;
    const float* src = nm + (size_t)bs * NN;
    float* dst       = out1 + (size_t)bs * NN;
    const float* ns  = normsq + (size_t)b * NN;
    int tid = threadIdx.x;
    float e[8];
    float sum = 0.f;
    #pragma unroll
    for (int i = 0; i < 8; ++i) {
        int n = i * 1024 + tid;
        float logit = src[n] * sqrtf(ns[n]);
        float v = (logit > 0.f) ? __expf(logit) : 0.f;
        e[i] = v;
        sum += v;
    }
    #pragma unroll
    for (int m = 1; m <= 32; m <<= 1) sum += __shfl_xor(sum, m, 64);
    int w = tid >> 6, lane = tid & 63;
    if (lane == 0) red[w] = sum;
    __syncthreads();
    float part = 0.f;
    #pragma unroll
    for (int j = 0; j < 16; ++j) part += red[j];
    float inv = (part > 0.f) ? (1.f / part) : 0.f;
    #pragma unroll
    for (int i = 0; i < 8; ++i) dst[i * 1024 + tid] = e[i] * inv;
}

// ---------------- kernel 3: pooling GEMM partials over 256-n chunks ----------------
// h-split x4 -> grid 1024 (4 blocks/CU = 16 waves/CU); bx%8 invariant in ht -> 4
// ht-blocks of one (b,c) share an XCD -> shared wgt slice L2-local.
__global__ __launch_bounds__(256) void pooled_k(
    const u16* __restrict__ xa, const float* __restrict__ wgt,
    float* __restrict__ part)
{
    __shared__ u16 lw[32 * 264];         // [s][k] stride 264 shorts (528 B)
    int bx = blockIdx.x;                 // 0..1023
    int ht = bx >> 8;                    // 0..3
    int bc = bx & 255;
    int b  = bc >> 5, c = bc & 31;
    int n0 = c * 256;
    int tid = threadIdx.x, w = tid >> 6, lane = tid & 63, quad = lane >> 4, l15 = lane & 15;

    // stage weights fp32 -> bf16 (32 s x 256 n); thread: s = tid>>3, n-sub = (tid&7)*32
    {
        int s  = tid >> 3;
        int nb = (tid & 7) * 32;
        const float* src = wgt + (size_t)(b * SS + s) * NN + n0 + nb;
        #pragma unroll
        for (int q = 0; q < 8; ++q) {
            float4 v = *reinterpret_cast<const float4*>(src + q * 4);
            uint2 pk;
            pk.x = pk2(v.x, v.y);
            pk.y = pk2(v.z, v.w);
            *reinterpret_cast<uint2*>(&lw[s * 264 + nb + q * 4]) = pk;
        }
    }
    __syncthreads();

    f32x4 acc[2];                        // [st]
    acc[0] = (f32x4){0.f, 0.f, 0.f, 0.f};
    acc[1] = (f32x4){0.f, 0.f, 0.f, 0.f};

    // A rows = h (16 per wave), k = n
    const u16* ab = xa + (size_t)b * ((size_t)HH * NN)
                  + (size_t)(ht * 64 + w * 16 + l15) * NN + n0;
    #pragma unroll
    for (int ks = 0; ks < 8; ++ks) {
        short8 av = *reinterpret_cast<const short8*>(ab + ks * 32 + quad * 8);
        #pragma unroll
        for (int st = 0; st < 2; ++st) {
            int s = st * 16 + l15;
            short8 bv = *reinterpret_cast<const short8*>(&lw[s * 264 + ks * 32 + quad * 8]);
            acc[st] = __builtin_amdgcn_mfma_f32_16x16x32_bf16(av, bv, acc[st], 0, 0, 0);
        }
    }
    float* pb = part + (size_t)(b * NCH + c) * 8192;   // [s*256 + h]
    #pragma unroll
    for (int st = 0; st < 2; ++st) {
        int h = ht * 64 + w * 16 + quad * 4;
        int s = st * 16 + l15;
        *reinterpret_cast<f32x4*>(&pb[s * 256 + h]) = acc[st];
    }
}

// ---------------- kernel 4: reduce partials over 32 chunks + tanh -> out0 ----------------
__global__ __launch_bounds__(256) void reduce_tanh(const float* __restrict__ part,
                                                   float* __restrict__ out0)
{
    int gid = blockIdx.x * 256 + threadIdx.x;   // 0..65535 = b*8192 + s*256 + h
    int b = gid >> 13, r = gid & 8191;
    const float* p = part + (size_t)b * NCH * 8192 + r;
    float s = 0.f;
    #pragma unroll
    for (int c = 0; c < NCH; ++c) s += p[(size_t)c * 8192];
    out0[gid] = tanhf(s);
}

extern "C" void kernel_launch(void* const* d_in, const int* in_sizes, int n_in,
                              void* d_out, int out_size, void* d_ws, size_t ws_size,
                              hipStream_t stream) {
    const float* x  = (const float*)d_in[0];
    const float* nm = (const float*)d_in[1];
    const float* Wi = (const float*)d_in[2];
    const float* bi = (const float*)d_in[3];
    const float* Wj = (const float*)d_in[4];
    const float* bj = (const float*)d_in[5];
    float* out0 = (float*)d_out;
    float* out1 = out0 + NB * SS * HH;           // 65536

    char* ws = (char*)d_ws;
    u16*   Wb     = (u16*)ws;                                    //    327,680 B
    u16*   xa     = (u16*)(ws + 327680);                         // 33,554,432 B
    float* normsq = (float*)(ws + 327680 + 33554432);            //    262,144 B
    float* part   = (float*)(ws + 327680 + 33554432 + 262144);   //  8,388,608 B

    prep_w     <<<640,  256, 0, stream>>>(Wi, Wj, Wb, normsq);
    gemm_gate  <<<1024, 512, 0, stream>>>(x, Wb, bi, bj, xa, normsq);
    softmax_k  <<<256, 1024, 0, stream>>>(nm, normsq, out1);
    pooled_k   <<<1024, 256, 0, stream>>>(xa, out1, part);
    reduce_tanh<<<256,  256, 0, stream>>>(part, out0);
}

// Round 9
// 197.121 us; speedup vs baseline: 1.0751x; 1.0068x over previous
//
#include <hip/hip_runtime.h>
#include <cstdint>
#include <cstddef>

typedef unsigned short u16;
typedef unsigned int   u32;
using short8 = __attribute__((ext_vector_type(8))) short;
using f32x4  = __attribute__((ext_vector_type(4))) float;

// B=8, N=8192, H=256, A=64 (F=320), S=32
#define NB    8
#define NN    8192
#define HH    256
#define FF    320
#define SS    32
#define NROWS 65536
#define NCH   32            // pooling K-split chunks (256 n each)

__device__ __forceinline__ u16 f2bf(float f) {
    union { float f; u32 u; } v; v.f = f;
    u32 r = v.u + 0x7fffu + ((v.u >> 16) & 1u);   // RNE
    return (u16)(r >> 16);
}
// HW packed f32->bf16 (RNE). No builtin on gfx950 -> inline asm (T12 recipe).
__device__ __forceinline__ u32 pk2(float lo, float hi) {
    u32 r;
    asm("v_cvt_pk_bf16_f32 %0, %1, %2" : "=v"(r) : "v"(lo), "v"(hi));
    return r;
}
__device__ __forceinline__ short8 pack8(float4 a, float4 b) {
    union { u32 u[4]; short8 s; } r;
    r.u[0] = pk2(a.x, a.y); r.u[1] = pk2(a.z, a.w);
    r.u[2] = pk2(b.x, b.y); r.u[3] = pk2(b.z, b.w);
    return r.s;
}

// ---------------- prep: cast Wi,Wj to bf16 (concat) + zero normsq ----------------
// x pre-cast ELIMINATED (R7 decision): gemm reads x fp32 directly, saving the 84 MB
// read + 42 MB write prep leg (~23 us) and 42 MB of xb16 re-read.
__global__ __launch_bounds__(256) void prep_w(const float* __restrict__ Wi,
                                              const float* __restrict__ Wj,
                                              u16* __restrict__ Wb,
                                              float* __restrict__ normsq) {
    int idx = blockIdx.x * 256 + threadIdx.x;       // 0..163839
    float v = (idx < 81920) ? Wi[idx] : Wj[idx - 81920];
    Wb[idx] = f2bf(v);
    if (idx < NROWS) normsq[idx] = 0.f;
}

// ---------------- kernel 1: gated features + norm^2 ----------------
// R8 version (kept; best-total config): A read fp32 float4-pairs ring depth-3, cast at
// use via v_cvt_pk. 512 thr / 8 waves, 256 rows x 128 cols, B full-K in LDS (80 KB).
__global__ __launch_bounds__(512, 3) void gemm_gate(
    const float* __restrict__ x, const u16* __restrict__ Wb,
    const float* __restrict__ bi, const float* __restrict__ bj,
    u16* __restrict__ xa, float* __restrict__ normsq)
{
    __shared__ u16 lB[5 * 8192];      // [kt][row 0..127][swizzled k-slot*8], 81920 B

    const int bx   = blockIdx.x;
    const int xcd  = bx & 7;
    const int ht   = (bx >> 3) & 3;
    const int slot = bx >> 5;         // 0..31
    const int mb   = xcd + slot * 8;  // 0..255
    const int m0   = mb * 256;
    const int h0   = ht * 64;
    const int b_idx = m0 >> 13;
    const int n0    = m0 & 8191;

    const int tid  = threadIdx.x;
    const int w    = tid >> 6;        // 0..7
    const int lane = tid & 63;
    const int quad = lane >> 4;
    const int l15  = lane & 15;

    // ---- one-time B load: 5 kt x 2 issues per wave (16 issues of 1 KB per kt) ----
    {
        const int rsub = lane >> 3;                 // 0..7
        const int kg   = (lane & 7) ^ rsub;         // XOR swizzle
        #pragma unroll
        for (int kt = 0; kt < 5; ++kt) {
            #pragma unroll
            for (int j = 0; j < 2; ++j) {
                int sl  = w * 2 + j;                // 0..15
                int row = sl * 8 + rsub;            // 0..127
                int mat = row >> 6, hl = row & 63;
                const u16* gsrc = Wb + mat * 81920 + (size_t)(h0 + hl) * FF + kt * 64 + kg * 8;
                u16* ldst = &lB[kt * 8192 + sl * 512];
                __builtin_amdgcn_global_load_lds(
                    (const __attribute__((address_space(1))) void*)gsrc,
                    (__attribute__((address_space(3))) void*)ldst, 16, 0, 0);
            }
        }
    }

    // ---- A fragment addressing: row = m0 + w*32 + mt*16 + l15, k = ks*32 + quad*8 ----
    const float* xb = x + (size_t)(m0 + w * 32 + l15) * FF + quad * 8;

    f32x4 acc[8][2];                  // [mn(col/16)][mt]
    #pragma unroll
    for (int a = 0; a < 8; ++a)
        #pragma unroll
        for (int m = 0; m < 2; ++m) acc[a][m] = (f32x4){0.f, 0.f, 0.f, 0.f};

    float4 pre[4][2][2];              // ring of 4 slots x mt x (lo,hi): depth 3
    #pragma unroll
    for (int p = 0; p < 3; ++p)
        #pragma unroll
        for (int mt = 0; mt < 2; ++mt) {
            pre[p][mt][0] = *reinterpret_cast<const float4*>(xb + mt * 16 * FF + p * 32);
            pre[p][mt][1] = *reinterpret_cast<const float4*>(xb + mt * 16 * FF + p * 32 + 4);
        }

    __syncthreads();                  // B resident

    #pragma unroll
    for (int ks = 0; ks < 10; ++ks) {
        const int cur = ks & 3;
        if (ks < 7) {
            const int nxt = (ks + 3) & 3;
            const int f   = (ks + 3) * 32;
            #pragma unroll
            for (int mt = 0; mt < 2; ++mt) {
                pre[nxt][mt][0] = *reinterpret_cast<const float4*>(xb + mt * 16 * FF + f);
                pre[nxt][mt][1] = *reinterpret_cast<const float4*>(xb + mt * 16 * FF + f + 4);
            }
        }
        // pin prefetch issue before this ks's compute group (R6: neutral-to-positive)
        __builtin_amdgcn_sched_barrier(0);
        short8 af[2];
        #pragma unroll
        for (int mt = 0; mt < 2; ++mt)
            af[mt] = pack8(pre[cur][mt][0], pre[cur][mt][1]);
        const int kt = ks >> 1, kk = ks & 1;
        #pragma unroll
        for (int mn = 0; mn < 8; ++mn) {
            int c = mn * 16 + l15;
            short8 bv = *reinterpret_cast<const short8*>(
                &lB[kt * 8192 + c * 64 + (((kk * 4 + quad) ^ (c & 7)) << 3)]);
            acc[mn][0] = __builtin_amdgcn_mfma_f32_16x16x32_bf16(af[0], bv, acc[mn][0], 0, 0, 0);
            acc[mn][1] = __builtin_amdgcn_mfma_f32_16x16x32_bf16(af[1], bv, acc[mn][1], 0, 0, 0);
        }
    }

    // ---- epilogue: gate, store xa [b][h][n], norm^2 ----
    float s0[2][4];
    #pragma unroll
    for (int mt = 0; mt < 2; ++mt)
        #pragma unroll
        for (int r = 0; r < 4; ++r) s0[mt][r] = 0.f;

    #pragma unroll
    for (int hq = 0; hq < 4; ++hq) {
        int h = h0 + hq * 16 + l15;
        float bi_v = bi[h], bj_v = bj[h];
        #pragma unroll
        for (int mt = 0; mt < 2; ++mt) {
            float xall[4];
            #pragma unroll
            for (int r = 0; r < 4; ++r) {
                float yi = acc[hq][mt][r] + bi_v;
                float yj = acc[hq + 4][mt][r] + bj_v;
                float sg = 1.f / (1.f + __expf(-yi));
                float e2 = __expf(-2.f * yj);
                float th = (1.f - e2) / (1.f + e2);
                float xv = sg * th;
                xall[r] = xv;
                s0[mt][r] += xv * xv;
            }
            uint2 pk;
            pk.x = pk2(xall[0], xall[1]);
            pk.y = pk2(xall[2], xall[3]);
            size_t o = (size_t)b_idx * ((size_t)HH * NN) + (size_t)h * NN
                     + (size_t)(n0 + w * 32 + mt * 16 + quad * 4);
            *reinterpret_cast<uint2*>(&xa[o]) = pk;
        }
    }
    #pragma unroll
    for (int m = 1; m <= 8; m <<= 1) {
        #pragma unroll
        for (int mt = 0; mt < 2; ++mt)
            #pragma unroll
            for (int r = 0; r < 4; ++r)
                s0[mt][r] += __shfl_xor(s0[mt][r], m, 64);
    }
    if (l15 == 0) {
        #pragma unroll
        for (int mt = 0; mt < 2; ++mt)
            #pragma unroll
            for (int r = 0; r < 4; ++r)
                atomicAdd(&normsq[m0 + w * 32 + mt * 16 + quad * 4 + r], s0[mt][r]);
    }
}

// ---------------- kernel 2: masked softmax over N per (b,s) -> out1 fp32 ----------------
__global__ __launch_bounds__(1024) void softmax_k(
    const float* __restrict__ nm, const float* __restrict__ normsq,
    float* __restrict__ out1)
{
    __shared__ float red[16];
    int bs = blockIdx.x;                 // 0..255
    int b  = bs >> 5;
    const float* src = nm + (size_t)bs * NN;
    float* dst       = out1 + (size_t)bs * NN;
    const float* ns  = normsq + (size_t)b * NN;
    int tid = threadIdx.x;
    float e[8];
    float sum = 0.f;
    #pragma unroll
    for (int i = 0; i < 8; ++i) {
        int n = i * 1024 + tid;
        float logit = src[n] * sqrtf(ns[n]);
        float v = (logit > 0.f) ? __expf(logit) : 0.f;
        e[i] = v;
        sum += v;
    }
    #pragma unroll
    for (int m = 1; m <= 32; m <<= 1) sum += __shfl_xor(sum, m, 64);
    int w = tid >> 6, lane = tid & 63;
    if (lane == 0) red[w] = sum;
    __syncthreads();
    float part = 0.f;
    #pragma unroll
    for (int j = 0; j < 16; ++j) part += red[j];
    float inv = (part > 0.f) ? (1.f / part) : 0.f;
    #pragma unroll
    for (int i = 0; i < 8; ++i) dst[i * 1024 + tid] = e[i] * inv;
}

// ---------------- kernel 3: pooling GEMM partials over 256-n chunks ----------------
// v4 (R9): xa tile STAGED through LDS via global_load_lds with gemm's proven 16 B XOR
// swizzle (linear dest + inverse-swizzled source + swizzled ds_read, rule #21). The old
// per-lane xa fragment gather (64 distinct 64 B lines per wave-load) was the kernel's
// cost, not occupancy (it already had 16 waves/CU). LDS 32 KB (xa) + 16.9 KB (wgt bf16)
// -> 3 blocks/CU. Grid 1024; bx%8 invariant in ht -> ht-blocks of one (b,c) share XCD.
__global__ __launch_bounds__(256) void pooled_k(
    const u16* __restrict__ xa, const float* __restrict__ wgt,
    float* __restrict__ part)
{
    __shared__ u16 lx[4 * 4096];         // 32 KB: [nt][sl][rsub][chunk^rsub] 16B units
    __shared__ u16 lw[32 * 264];         // [s][k] stride 264 shorts (528 B)
    int bx = blockIdx.x;                 // 0..1023
    int ht = bx >> 8;                    // 0..3
    int bc = bx & 255;
    int b  = bc >> 5, c = bc & 31;
    int n0 = c * 256;
    int tid = threadIdx.x, w = tid >> 6, lane = tid & 63, quad = lane >> 4, l15 = lane & 15;

    // ---- stage xa tile (64 h x 256 n bf16) -> lx, coalesced + XOR-swizzled source ----
    // row r = local h (0..63); per nt (64 n = 8 chunks of 16 B): lane rsub = lane>>3,
    // chunk kg = (lane&7) ^ rsub. Linear LDS dest; read side applies the same XOR.
    {
        const int rsub = lane >> 3;                 // 0..7
        const int kg   = (lane & 7) ^ rsub;
        const u16* xbase = xa + (size_t)b * ((size_t)HH * NN)
                         + (size_t)(ht * 64) * NN + n0;
        #pragma unroll
        for (int nt = 0; nt < 4; ++nt) {
            #pragma unroll
            for (int j = 0; j < 2; ++j) {
                int sl  = w * 2 + j;                // 0..7 row-block
                int row = sl * 8 + rsub;            // 0..63
                const u16* gsrc = xbase + (size_t)row * NN + nt * 64 + kg * 8;
                u16* ldst = &lx[nt * 4096 + sl * 512];
                __builtin_amdgcn_global_load_lds(
                    (const __attribute__((address_space(1))) void*)gsrc,
                    (__attribute__((address_space(3))) void*)ldst, 16, 0, 0);
            }
        }
    }

    // ---- stage weights fp32 -> bf16 (32 s x 256 n); thread: s = tid>>3, n-sub = (tid&7)*32
    {
        int s  = tid >> 3;
        int nb = (tid & 7) * 32;
        const float* src = wgt + (size_t)(b * SS + s) * NN + n0 + nb;
        #pragma unroll
        for (int q = 0; q < 8; ++q) {
            float4 v = *reinterpret_cast<const float4*>(src + q * 4);
            uint2 pk;
            pk.x = pk2(v.x, v.y);
            pk.y = pk2(v.z, v.w);
            *reinterpret_cast<uint2*>(&lw[s * 264 + nb + q * 4]) = pk;
        }
    }
    __syncthreads();

    f32x4 acc[2];                        // [st]
    acc[0] = (f32x4){0.f, 0.f, 0.f, 0.f};
    acc[1] = (f32x4){0.f, 0.f, 0.f, 0.f};

    // A rows = h (16 per wave, r = w*16 + l15), k = n from swizzled LDS
    const int r = w * 16 + l15;
    #pragma unroll
    for (int ks = 0; ks < 8; ++ks) {
        const int nt = ks >> 1;
        const int g  = (ks & 1) * 4 + quad;   // 16B chunk index within nt
        short8 av = *reinterpret_cast<const short8*>(
            &lx[nt * 4096 + (r >> 3) * 512 + (r & 7) * 64 + ((g ^ (r & 7)) << 3)]);
        #pragma unroll
        for (int st = 0; st < 2; ++st) {
            int s = st * 16 + l15;
            short8 bv = *reinterpret_cast<const short8*>(&lw[s * 264 + ks * 32 + quad * 8]);
            acc[st] = __builtin_amdgcn_mfma_f32_16x16x32_bf16(av, bv, acc[st], 0, 0, 0);
        }
    }
    float* pb = part + (size_t)(b * NCH + c) * 8192;   // [s*256 + h]
    #pragma unroll
    for (int st = 0; st < 2; ++st) {
        int h = ht * 64 + w * 16 + quad * 4;
        int s = st * 16 + l15;
        *reinterpret_cast<f32x4*>(&pb[s * 256 + h]) = acc[st];
    }
}

// ---------------- kernel 4: reduce partials over 32 chunks + tanh -> out0 ----------------
__global__ __launch_bounds__(256) void reduce_tanh(const float* __restrict__ part,
                                                   float* __restrict__ out0)
{
    int gid = blockIdx.x * 256 + threadIdx.x;   // 0..65535 = b*8192 + s*256 + h
    int b = gid >> 13, r = gid & 8191;
    const float* p = part + (size_t)b * NCH * 8192 + r;
    float s = 0.f;
    #pragma unroll
    for (int c = 0; c < NCH; ++c) s += p[(size_t)c * 8192];
    out0[gid] = tanhf(s);
}

extern "C" void kernel_launch(void* const* d_in, const int* in_sizes, int n_in,
                              void* d_out, int out_size, void* d_ws, size_t ws_size,
                              hipStream_t stream) {
    const float* x  = (const float*)d_in[0];
    const float* nm = (const float*)d_in[1];
    const float* Wi = (const float*)d_in[2];
    const float* bi = (const float*)d_in[3];
    const float* Wj = (const float*)d_in[4];
    const float* bj = (const float*)d_in[5];
    float* out0 = (float*)d_out;
    float* out1 = out0 + NB * SS * HH;           // 65536

    char* ws = (char*)d_ws;
    u16*   Wb     = (u16*)ws;                                    //    327,680 B
    u16*   xa     = (u16*)(ws + 327680);                         // 33,554,432 B
    float* normsq = (float*)(ws + 327680 + 33554432);            //    262,144 B
    float* part   = (float*)(ws + 327680 + 33554432 + 262144);   //  8,388,608 B

    prep_w     <<<640,  256, 0, stream>>>(Wi, Wj, Wb, normsq);
    gemm_gate  <<<1024, 512, 0, stream>>>(x, Wb, bi, bj, xa, normsq);
    softmax_k  <<<256, 1024, 0, stream>>>(nm, normsq, out1);
    pooled_k   <<<1024, 256, 0, stream>>>(xa, out1, part);
    reduce_tanh<<<256,  256, 0, stream>>>(part, out0);
}